// Round 7
// baseline (101.718 us; speedup 1.0000x reference)
//
#include <hip/hip_runtime.h>

#define TPB 256
#define R 16          // source points per lane
#define CHUNKS 128    // CH = n/CHUNKS = 128 targets per block
// n=16384: SB = n/(TPB*R) = 4 source-blocks/dir; grid = 2*SB*CHUNKS = 1024 blocks
// __launch_bounds__(256,4): VGPR cap 128; R=16 needs ~105 -> no loop fission.

// Pack {x,y,z,|p|^2}; init pmins = 0xFFFFFFFF (uint-max), acc/cnt = 0.
__global__ __launch_bounds__(TPB) void prep_kernel(
        const float* __restrict__ a, const float* __restrict__ b,
        float4* __restrict__ pa, float4* __restrict__ pb,
        unsigned* __restrict__ pmins, float* __restrict__ acc,
        unsigned* __restrict__ cnt, int n) {
    int idx = blockIdx.x * blockDim.x + threadIdx.x;
    if (idx < n) {
        float x = a[3 * idx], y = a[3 * idx + 1], z = a[3 * idx + 2];
        pa[idx] = make_float4(x, y, z, x * x + y * y + z * z);
    } else if (idx < 2 * n) {
        int i = idx - n;
        float x = b[3 * i], y = b[3 * i + 1], z = b[3 * i + 2];
        pb[i] = make_float4(x, y, z, x * x + y * y + z * z);
    }
    if (idx < 2 * n) pmins[idx] = 0xFFFFFFFFu;
    if (idx == 0) { acc[0] = 0.0f; cnt[0] = 0u; }
}

// min_t(|s-t|^2) = |s|^2 + min_t(|t|^2 - 2 s.t)
__global__ __launch_bounds__(TPB, 4) void minpass_kernel(
        const float4* __restrict__ pa, const float4* __restrict__ pb,
        unsigned* __restrict__ pmins, int n) {
    const int SB = n / (TPB * R);
    const int CH = n / CHUNKS;   // 128
    int b = blockIdx.x;
    int dir = b / (SB * CHUNKS);
    int rem = b % (SB * CHUNKS);
    int chunk = rem / SB;
    int sblk = rem % SB;
    const float4* __restrict__ src = dir ? pb : pa;
    const float4* __restrict__ tgt = dir ? pa : pb;

    __shared__ float4 tile[128];  // CH == 128
    int base = chunk * CH;
    for (int i = threadIdx.x; i < CH; i += TPB)
        tile[i] = tgt[base + i];

    float ax[R], ay[R], az[R], sw[R], m[R];
    int s0 = sblk * TPB * R + threadIdx.x;  // stride-TPB between r's: coalesced
#pragma unroll
    for (int r = 0; r < R; ++r) {
        float4 s = src[s0 + r * TPB];
        ax[r] = -2.0f * s.x; ay[r] = -2.0f * s.y; az[r] = -2.0f * s.z;
        sw[r] = s.w; m[r] = __builtin_inff();
    }
    __syncthreads();

    // 2 targets/iter: per r, 6 v_fma + 1 v_min3; one b128 feeds 112 VALU insts
#pragma unroll 2
    for (int j = 0; j < CH; j += 2) {
        float4 p0 = tile[j];
        float4 p1 = tile[j + 1];
#pragma unroll
        for (int r = 0; r < R; ++r) {
            float d0 = fmaf(ax[r], p0.x, fmaf(ay[r], p0.y, fmaf(az[r], p0.z, p0.w)));
            float d1 = fmaf(ax[r], p1.x, fmaf(ay[r], p1.y, fmaf(az[r], p1.z, p1.w)));
            m[r] = fminf(m[r], fminf(d0, d1));  // -> v_min3_f32
        }
    }

    // nonneg floats monotone under unsigned compare -> uint atomicMin
#pragma unroll
    for (int r = 0; r < R; ++r)
        atomicMin(&pmins[dir * n + s0 + r * TPB], __float_as_uint(m[r] + sw[r]));
}

// 32 blocks x 256 threads: each thread sums one uint4; atomicAdd + gated out.
__global__ __launch_bounds__(TPB) void finalize_kernel(
        const uint4* __restrict__ pmins, float* __restrict__ acc,
        unsigned* __restrict__ cnt, float* __restrict__ out, int n, int nblocks) {
    int i = blockIdx.x * TPB + threadIdx.x;  // i-th uint4, total 2n/4
    uint4 v = pmins[i];
    float sum = __uint_as_float(v.x) + __uint_as_float(v.y)
              + __uint_as_float(v.z) + __uint_as_float(v.w);
    for (int off = 32; off > 0; off >>= 1)
        sum += __shfl_down(sum, off, 64);
    __shared__ float wsum[TPB / 64];
    int lane = threadIdx.x & 63, wid = threadIdx.x >> 6;
    if (lane == 0) wsum[wid] = sum;
    __syncthreads();
    if (threadIdx.x == 0) {
        float t = 0.0f;
        for (int w = 0; w < TPB / 64; ++w) t += wsum[w];
        atomicAdd(acc, t);
        __threadfence();
        unsigned old = atomicAdd(cnt, 1u);
        if (old == (unsigned)(nblocks - 1)) {
            float a0 = atomicAdd(acc, 0.0f);  // device-scope coherent read
            out[0] = a0 / (float)(2 * n);
        }
    }
}

extern "C" void kernel_launch(void* const* d_in, const int* in_sizes, int n_in,
                              void* d_out, int out_size, void* d_ws, size_t ws_size,
                              hipStream_t stream) {
    const float* a = (const float*)d_in[0];
    const float* b = (const float*)d_in[1];
    int n = in_sizes[0] / 3;  // 16384
    float* out = (float*)d_out;
    char* ws = (char*)d_ws;
    float* acc = (float*)ws;                 // 1 float
    unsigned* cnt = (unsigned*)(ws + 8);     // 1 uint
    float4* pa = (float4*)(ws + 256);
    float4* pb = pa + n;
    unsigned* pmins = (unsigned*)(ws + 256 + 2 * (size_t)n * sizeof(float4));

    prep_kernel<<<(2 * n + TPB - 1) / TPB, TPB, 0, stream>>>(
        a, b, pa, pb, pmins, acc, cnt, n);
    int SB = n / (TPB * R);
    minpass_kernel<<<2 * SB * CHUNKS, TPB, 0, stream>>>(pa, pb, pmins, n);
    int fblocks = (2 * n / 4) / TPB;  // 32
    finalize_kernel<<<fblocks, TPB, 0, stream>>>(
        (const uint4*)pmins, acc, cnt, out, n, fblocks);
}